// Round 1
// baseline (451.906 us; speedup 1.0000x reference)
//
#include <hip/hip_runtime.h>

#define NV   12288
#define CIN  128
#define COUT 128
#define DEG  9
#define NB   8
#define NROWS (NB * NV)   // 98304
#define BM 128
#define BN 128
#define BK 32

// ---------------------------------------------------------------------------
// SpMM: out[b,v,c] = sum_e vals[v,e] * src[b, cols[v,e], c]        (sub==null)
//       out[b,v,c] = 2*sum_e(...) - sub[b,v,c]                     (sub!=null)
// Layout [B, V, C] row-major. One block per vertex, 256 thr, float4/thread.
// sub may alias out (each thread reads exactly the element it writes).
// ---------------------------------------------------------------------------
__global__ __launch_bounds__(256)
void spmm_kernel(const float* __restrict__ src, const float* __restrict__ sub,
                 float* __restrict__ outp,
                 const int* __restrict__ cols, const float* __restrict__ vals)
{
    const int v   = blockIdx.x;
    const int idx = threadIdx.x * 4;       // (b,c) flat index, 4 consecutive c
    const int b   = idx >> 7;
    const int c   = idx & 127;

    int   ec[DEG];
    float ev[DEG];
#pragma unroll
    for (int e = 0; e < DEG; ++e) {        // v is block-uniform -> s_load
        ec[e] = cols[v * DEG + e];
        ev[e] = vals[v * DEG + e];
    }

    float ax = 0.f, ay = 0.f, az = 0.f, aw = 0.f;
    const size_t bofs = (size_t)b * NV;
#pragma unroll
    for (int e = 0; e < DEG; ++e) {
        const float4 s = *reinterpret_cast<const float4*>(
            &src[(bofs + (size_t)ec[e]) * CIN + c]);
        ax = fmaf(ev[e], s.x, ax);
        ay = fmaf(ev[e], s.y, ay);
        az = fmaf(ev[e], s.z, az);
        aw = fmaf(ev[e], s.w, aw);
    }

    float4 r;
    if (sub != nullptr) {
        const float4 s0 = *reinterpret_cast<const float4*>(
            &sub[(bofs + v) * CIN + c]);
        r.x = 2.f * ax - s0.x;
        r.y = 2.f * ay - s0.y;
        r.z = 2.f * az - s0.z;
        r.w = 2.f * aw - s0.w;
    } else {
        r.x = ax; r.y = ay; r.z = az; r.w = aw;
    }
    *reinterpret_cast<float4*>(&outp[(bofs + v) * CIN + c]) = r;
}

// ---------------------------------------------------------------------------
// GEMM: conv[r,o] (+)= sum_{segments s} sum_c Aseg[r,c] * W[(c*4 + wk_s)*128 + o]
// r in [0, NROWS). 128x128 tile, BK=32, 8x8 micro-tile, 256 threads.
// Optional: accumulate into existing conv; fused BN sum/sumsq atomics.
// ---------------------------------------------------------------------------
__global__ __launch_bounds__(256)
void gemm_kernel(const float* __restrict__ A0, const float* __restrict__ A1,
                 const float* __restrict__ A2, const float* __restrict__ A3,
                 int w0, int w1, int w2, int w3, int nseg,
                 const float* __restrict__ W, float* __restrict__ conv,
                 float* __restrict__ stats, int accumulate, int do_stats)
{
    __shared__ float As[BK][BM + 1];   // +1 pad: conflict-free scalar reads
    __shared__ float Ws[BK][BN];

    const int t  = threadIdx.x;
    const int tr = t >> 4;             // 0..15 (row group)
    const int tc = t & 15;             // 0..15 (col group)
    const int rbase = blockIdx.x * BM;

    float acc[8][8];
#pragma unroll
    for (int i = 0; i < 8; ++i)
#pragma unroll
        for (int j = 0; j < 8; ++j) acc[i][j] = 0.f;

#pragma unroll
    for (int s = 0; s < 4; ++s) {
        if (s >= nseg) break;
        const float* Aseg = (s == 0) ? A0 : (s == 1) ? A1 : (s == 2) ? A2 : A3;
        const int    wk   = (s == 0) ? w0 : (s == 1) ? w1 : (s == 2) ? w2 : w3;

        for (int ct = 0; ct < CIN / BK; ++ct) {
            const int cb = ct * BK;
            // stage A tile (BM rows x BK cols), transposed into As[k][row]
            {
                const int rr0 = t >> 3;           // 0..31
                const int c0  = (t & 7) * 4;      // 0..28
#pragma unroll
                for (int p = 0; p < 4; ++p) {
                    const int rr = rr0 + p * 32;
                    const float4 d = *reinterpret_cast<const float4*>(
                        &Aseg[(size_t)(rbase + rr) * CIN + cb + c0]);
                    As[c0 + 0][rr] = d.x;
                    As[c0 + 1][rr] = d.y;
                    As[c0 + 2][rr] = d.z;
                    As[c0 + 3][rr] = d.w;
                }
            }
            // stage W tile (BK x BN): global row = (cb+kk)*4 + wk
            {
                const int kk0 = t >> 5;           // 0..7
                const int o0  = (t & 31) * 4;     // 0..124
#pragma unroll
                for (int p = 0; p < 4; ++p) {
                    const int kk = kk0 + p * 8;
                    *reinterpret_cast<float4*>(&Ws[kk][o0]) =
                        *reinterpret_cast<const float4*>(
                            &W[(size_t)((cb + kk) * 4 + wk) * COUT + o0]);
                }
            }
            __syncthreads();
#pragma unroll
            for (int kk = 0; kk < BK; ++kk) {
                float a[8], w[8];
#pragma unroll
                for (int i = 0; i < 8; ++i) a[i] = As[kk][tr * 8 + i];
                *reinterpret_cast<float4*>(&w[0]) =
                    *reinterpret_cast<const float4*>(&Ws[kk][tc * 8]);
                *reinterpret_cast<float4*>(&w[4]) =
                    *reinterpret_cast<const float4*>(&Ws[kk][tc * 8 + 4]);
#pragma unroll
                for (int i = 0; i < 8; ++i)
#pragma unroll
                    for (int j = 0; j < 8; ++j)
                        acc[i][j] = fmaf(a[i], w[j], acc[i][j]);
            }
            __syncthreads();
        }
    }

    // epilogue: write conv, optionally fold BN partial stats
    float cs[8], cq[8];
#pragma unroll
    for (int j = 0; j < 8; ++j) { cs[j] = 0.f; cq[j] = 0.f; }

#pragma unroll
    for (int i = 0; i < 8; ++i) {
        float* cp = &conv[(size_t)(rbase + tr * 8 + i) * COUT + tc * 8];
        float vr[8];
#pragma unroll
        for (int j = 0; j < 8; ++j) vr[j] = acc[i][j];
        if (accumulate) {
            const float4 o0 = *reinterpret_cast<const float4*>(cp);
            const float4 o1 = *reinterpret_cast<const float4*>(cp + 4);
            vr[0] += o0.x; vr[1] += o0.y; vr[2] += o0.z; vr[3] += o0.w;
            vr[4] += o1.x; vr[5] += o1.y; vr[6] += o1.z; vr[7] += o1.w;
        }
        const float4 r0 = {vr[0], vr[1], vr[2], vr[3]};
        const float4 r1 = {vr[4], vr[5], vr[6], vr[7]};
        *reinterpret_cast<float4*>(cp)     = r0;
        *reinterpret_cast<float4*>(cp + 4) = r1;
        if (do_stats) {
#pragma unroll
            for (int j = 0; j < 8; ++j) {
                cs[j] += vr[j];
                cq[j] = fmaf(vr[j], vr[j], cq[j]);
            }
        }
    }

    if (do_stats) {
        float (*redS)[COUT] = reinterpret_cast<float(*)[COUT]>(&As[0][0]);
        float (*redQ)[COUT] = reinterpret_cast<float(*)[COUT]>(&Ws[0][0]);
        __syncthreads();
#pragma unroll
        for (int j = 0; j < 8; ++j) {
            redS[tr][tc * 8 + j] = cs[j];
            redQ[tr][tc * 8 + j] = cq[j];
        }
        __syncthreads();
        if (t < COUT) {
            float S = 0.f, Q = 0.f;
#pragma unroll
            for (int rr = 0; rr < 16; ++rr) { S += redS[rr][t]; Q += redQ[rr][t]; }
            atomicAdd(&stats[t], S);
            atomicAdd(&stats[COUT + t], Q);
        }
    }
}

// ---------------------------------------------------------------------------
// BN finalize: stats[0:128]=sum, [128:256]=sumsq -> [256:384]=scale, [384:512]=shift
// ---------------------------------------------------------------------------
__global__ __launch_bounds__(128)
void bn_finalize(float* __restrict__ stats, const float* __restrict__ gamma,
                 const float* __restrict__ beta)
{
    const int o = threadIdx.x;
    if (o < COUT) {
        const float invN = 1.0f / (float)NROWS;
        const float mean = stats[o] * invN;
        const float var  = stats[COUT + o] * invN - mean * mean;
        const float rsig = rsqrtf(var + 1e-5f);
        const float sc   = rsig * gamma[o];
        stats[2 * COUT + o] = sc;
        stats[3 * COUT + o] = beta[o] - mean * sc;
    }
}

// ---------------------------------------------------------------------------
// Transpose + normalize: out[b,o,v] = conv[b,v,o]*scale[o] + shift[o]
// 64(v) x 128(o) LDS tile per block.
// ---------------------------------------------------------------------------
__global__ __launch_bounds__(256)
void transpose_bn(const float* __restrict__ conv, const float* __restrict__ stats,
                  float* __restrict__ outp)
{
    __shared__ float tile[64][129];
    const int t  = threadIdx.x;
    const int nb = NV / 64;                 // 192
    const int b  = blockIdx.x / nb;
    const int v0 = (blockIdx.x % nb) * 64;

    {   // load conv[b, v0+vv, :]
        const int vv0 = t >> 5;             // 0..7
        const int o0  = (t & 31) * 4;       // 0..124
#pragma unroll
        for (int p = 0; p < 8; ++p) {
            const int vv = vv0 + p * 8;
            const float4 d = *reinterpret_cast<const float4*>(
                &conv[((size_t)b * NV + v0 + vv) * COUT + o0]);
            tile[vv][o0 + 0] = d.x;
            tile[vv][o0 + 1] = d.y;
            tile[vv][o0 + 2] = d.z;
            tile[vv][o0 + 3] = d.w;
        }
    }
    __syncthreads();
    {   // write out[b, o, v0+vvb..vvb+3]
        const int vvb = (t & 15) * 4;       // 0..60
        const int o0  = t >> 4;             // 0..15
#pragma unroll
        for (int p = 0; p < 8; ++p) {
            const int o  = o0 + p * 16;
            const float sc = stats[2 * COUT + o];
            const float sh = stats[3 * COUT + o];
            float4 r;
            r.x = fmaf(tile[vvb + 0][o], sc, sh);
            r.y = fmaf(tile[vvb + 1][o], sc, sh);
            r.z = fmaf(tile[vvb + 2][o], sc, sh);
            r.w = fmaf(tile[vvb + 3][o], sc, sh);
            *reinterpret_cast<float4*>(
                &outp[((size_t)b * COUT + o) * NV + v0 + vvb]) = r;
        }
    }
}

// ---------------------------------------------------------------------------
extern "C" void kernel_launch(void* const* d_in, const int* in_sizes, int n_in,
                              void* d_out, int out_size, void* d_ws, size_t ws_size,
                              hipStream_t stream)
{
    (void)in_sizes; (void)n_in; (void)out_size;

    const float* x     = (const float*)d_in[0];
    const int*   cols  = (const int*)  d_in[2];
    const float* vals  = (const float*)d_in[3];
    const float* W     = (const float*)d_in[4];
    const float* gamma = (const float*)d_in[5];
    const float* beta  = (const float*)d_in[6];
    float*       out   = (float*)d_out;

    const size_t bufElems = (size_t)NB * NV * CIN;   // 12,582,912 floats

    float* conv = (float*)d_ws;
    float* Ta   = conv + bufElems;
    float* Tb   = Ta + bufElems;
    float* Tc   = Tb + bufElems;

    const bool big = ws_size >= (4 * bufElems + 1024) * sizeof(float);
    float* stats = (big ? Tc : Tb) + bufElems;       // 512 floats

    const dim3 blk(256);
    const int gemm_grid = NROWS / BM;                // 768
    const int tr_grid   = NB * (NV / 64);            // 1536

    // T1 = L x
    spmm_kernel<<<NV, blk, 0, stream>>>(x, nullptr, Ta, cols, vals);
    // T2 = 2 L T1 - x
    spmm_kernel<<<NV, blk, 0, stream>>>(Ta, x, Tb, cols, vals);

    hipMemsetAsync(stats, 0, 2 * COUT * sizeof(float), stream);

    if (big) {
        // T3 = 2 L T2 - T1
        spmm_kernel<<<NV, blk, 0, stream>>>(Tb, Ta, Tc, cols, vals);
        // conv = x W0 + T1 W1 + T2 W2 + T3 W3  (+ fused BN stats)
        gemm_kernel<<<gemm_grid, blk, 0, stream>>>(x, Ta, Tb, Tc, 0, 1, 2, 3, 4,
                                                   W, conv, stats, 0, 1);
    } else {
        // conv = x W0 + T1 W1 + T2 W2
        gemm_kernel<<<gemm_grid, blk, 0, stream>>>(x, Ta, Tb, Tb, 0, 1, 2, 2, 3,
                                                   W, conv, stats, 0, 0);
        // T3 = 2 L T2 - T1   (in place over Ta)
        spmm_kernel<<<NV, blk, 0, stream>>>(Tb, Ta, Ta, cols, vals);
        // conv += T3 W3  (+ fused BN stats on final values)
        gemm_kernel<<<gemm_grid, blk, 0, stream>>>(Ta, Ta, Ta, Ta, 3, 3, 3, 3, 1,
                                                   W, conv, stats, 1, 1);
    }

    bn_finalize<<<1, 128, 0, stream>>>(stats, gamma, beta);
    transpose_bn<<<tr_grid, blk, 0, stream>>>(conv, stats, out);
}

// Round 2
// 178.175 us; speedup vs baseline: 2.5363x; 2.5363x over previous
//
#include <hip/hip_runtime.h>

#define NV    12288
#define CIN   128
#define COUT  128
#define DEG   9
#define NB    8
#define NROWS (NB * NV)        // 98304
#define KTOT  512              // 4 segments * 128

typedef unsigned short bfu;
typedef __attribute__((ext_vector_type(8))) short short8;
typedef __attribute__((ext_vector_type(4))) float floatx4;
typedef __attribute__((ext_vector_type(4))) unsigned short ushort4v;

__device__ __forceinline__ float bf2f(unsigned short u) {
    union { unsigned int i; float f; } x;
    x.i = ((unsigned int)u) << 16;
    return x.f;
}
__device__ __forceinline__ unsigned short f2bf(float f) {
    union { float f; unsigned int i; } x;
    x.f = f;
    unsigned int r = x.i + 0x7FFFu + ((x.i >> 16) & 1u);   // round-nearest-even
    return (unsigned short)(r >> 16);
}
__device__ __forceinline__ void gload16(const void* g, void* l) {
    __builtin_amdgcn_global_load_lds(
        (const __attribute__((address_space(1))) unsigned int*)g,
        (__attribute__((address_space(3))) unsigned int*)l, 16, 0, 0);
}

// ---------------------------------------------------------------------------
// x (fp32) -> xb (bf16), 8 elems/thread
// ---------------------------------------------------------------------------
__global__ __launch_bounds__(256)
void convert_x(const float* __restrict__ x, bfu* __restrict__ xb)
{
    const size_t i = ((size_t)blockIdx.x * 256 + threadIdx.x) * 8;
    const float4 a = *reinterpret_cast<const float4*>(x + i);
    const float4 b = *reinterpret_cast<const float4*>(x + i + 4);
    short8 r;
    r[0] = (short)f2bf(a.x); r[1] = (short)f2bf(a.y);
    r[2] = (short)f2bf(a.z); r[3] = (short)f2bf(a.w);
    r[4] = (short)f2bf(b.x); r[5] = (short)f2bf(b.y);
    r[6] = (short)f2bf(b.z); r[7] = (short)f2bf(b.w);
    *reinterpret_cast<short8*>(xb + i) = r;
}

// ---------------------------------------------------------------------------
// W[(c*4+s)*128 + o] (fp32) -> Wt[o*512 + s*128 + c] (bf16)
// ---------------------------------------------------------------------------
__global__ __launch_bounds__(256)
void build_wt(const float* __restrict__ W, bfu* __restrict__ Wt)
{
    const int i = blockIdx.x * 256 + threadIdx.x;      // 65536 total
    const int o = i >> 9;
    const int kap = i & 511;
    const int s = kap >> 7;
    const int c = kap & 127;
    Wt[i] = f2bf(W[(size_t)(c * 4 + s) * COUT + o]);
}

// ---------------------------------------------------------------------------
// SpMM in bf16 storage, fp32 math.
//   out[b,v,c] = sum_e vals[v,e]*src[b,cols[v,e],c]          (sub==null)
//   out[b,v,c] = 2*sum - sub[b,v,c]                          (sub!=null)
// 256 thr = 2 vertices/block; thread handles (b, c0..c0+7).
// ---------------------------------------------------------------------------
__global__ __launch_bounds__(256)
void spmm_bf16(const bfu* __restrict__ src, const bfu* __restrict__ sub,
               bfu* __restrict__ outp, const int* __restrict__ cols,
               const float* __restrict__ vals)
{
    const int t  = threadIdx.x;
    const int v  = blockIdx.x * 2 + (t >> 7);
    const int tt = t & 127;
    const int b  = tt >> 4;
    const int c0 = (tt & 15) * 8;

    int   ec[DEG];
    float ev[DEG];
#pragma unroll
    for (int e = 0; e < DEG; ++e) {
        ec[e] = cols[v * DEG + e];
        ev[e] = vals[v * DEG + e];
    }

    float acc[8];
#pragma unroll
    for (int j = 0; j < 8; ++j) acc[j] = 0.f;

    const size_t bbase = (size_t)b * NV * CIN;
#pragma unroll
    for (int e = 0; e < DEG; ++e) {
        const short8 s = *reinterpret_cast<const short8*>(
            src + bbase + (size_t)ec[e] * CIN + c0);
#pragma unroll
        for (int j = 0; j < 8; ++j)
            acc[j] = fmaf(ev[e], bf2f((unsigned short)s[j]), acc[j]);
    }

    if (sub != nullptr) {
        const short8 s0 = *reinterpret_cast<const short8*>(
            sub + bbase + (size_t)v * CIN + c0);
#pragma unroll
        for (int j = 0; j < 8; ++j)
            acc[j] = 2.f * acc[j] - bf2f((unsigned short)s0[j]);
    }

    short8 r;
#pragma unroll
    for (int j = 0; j < 8; ++j) r[j] = (short)f2bf(acc[j]);
    *reinterpret_cast<short8*>(outp + bbase + (size_t)v * CIN + c0) = r;
}

// ---------------------------------------------------------------------------
// MFMA GEMM: convT[b,o,v] = sum_k A[r=b*V+v, k] * Wt[o, k]   (K=512)
// A = 4 bf16 segments [98304][128]. 128x128 tile, BK=64, 4 waves (2x2),
// wave tile 64x64 = 4x4 frags of mfma_f32_16x16x32_bf16.
// LDS XOR-swizzle via pre-swizzled global_load_lds source.
// Fused BN sum/sumsq -> gstats atomics.
// ---------------------------------------------------------------------------
__global__ __launch_bounds__(256)
void gemm_mfma(const bfu* __restrict__ A0, const bfu* __restrict__ A1,
               const bfu* __restrict__ A2, const bfu* __restrict__ A3,
               const bfu* __restrict__ Wt, bfu* __restrict__ convT,
               float* __restrict__ gstats)
{
    __shared__ char smem[33792];                  // A 16K | B 16K | sred/qred 1K
    float* sred = (float*)(smem + 32768);
    float* qred = sred + COUT;

    const int t    = threadIdx.x;
    const int lane = t & 63;
    const int wid  = t >> 6;
    const int wr   = wid >> 1;                    // 0..1 row-wave
    const int wc   = wid & 1;                     // 0..1 col-wave
    const int rbase = blockIdx.x * 128;
    const int ck   = t & 7;                       // 16B chunk id for staging

    if (t < COUT) { sred[t] = 0.f; qred[t] = 0.f; }

    floatx4 acc[4][4];
#pragma unroll
    for (int m = 0; m < 4; ++m)
#pragma unroll
        for (int n = 0; n < 4; ++n) acc[m][n] = (floatx4){0.f, 0.f, 0.f, 0.f};

    const bfu* segs[4] = {A0, A1, A2, A3};

#pragma unroll
    for (int kt = 0; kt < 8; ++kt) {
        const bfu* As = segs[kt >> 1];            // unrolled -> compile-time
        const int  cb = (kt & 1) * 64;
        // stage A tile [128 rows][64 cols] bf16, source pre-swizzled
#pragma unroll
        for (int p = 0; p < 4; ++p) {
            const int flat = p * 256 + t;
            const int rr   = flat >> 3;
            gload16(As + (size_t)(rbase + rr) * CIN + cb + ((ck ^ (rr & 7)) << 3),
                    smem + flat * 16);
        }
        // stage B tile [128 o-rows][64 k] bf16 from Wt
#pragma unroll
        for (int p = 0; p < 4; ++p) {
            const int flat = p * 256 + t;
            const int n    = flat >> 3;
            gload16(Wt + (size_t)n * KTOT + kt * 64 + ((ck ^ (n & 7)) << 3),
                    smem + 16384 + flat * 16);
        }
        __syncthreads();
#pragma unroll
        for (int ks = 0; ks < 2; ++ks) {
            const int chunk = ((ks * 4 + (lane >> 4)) ^ (lane & 7)) * 16;
            short8 a[4], b[4];
#pragma unroll
            for (int m = 0; m < 4; ++m)
                a[m] = *reinterpret_cast<const short8*>(
                    smem + (wr * 64 + m * 16 + (lane & 15)) * 128 + chunk);
#pragma unroll
            for (int n = 0; n < 4; ++n)
                b[n] = *reinterpret_cast<const short8*>(
                    smem + 16384 + (wc * 64 + n * 16 + (lane & 15)) * 128 + chunk);
#pragma unroll
            for (int m = 0; m < 4; ++m)
#pragma unroll
                for (int n = 0; n < 4; ++n)
                    acc[m][n] = __builtin_amdgcn_mfma_f32_16x16x32_bf16(
                        a[m], b[n], acc[m][n], 0, 0, 0);
        }
        __syncthreads();
    }

    // epilogue: convT[b,o,v] bf16 + BN partial stats
    const int batch = rbase / NV;                 // block never straddles batch
    const int v0 = (rbase % NV) + wr * 64 + (lane >> 4) * 4;
    const int ob = wc * 64 + (lane & 15);

#pragma unroll
    for (int n = 0; n < 4; ++n) {
        const int o = ob + n * 16;
        float s = 0.f, q = 0.f;
        bfu* cbase = convT + ((size_t)batch * COUT + o) * NV + v0;
#pragma unroll
        for (int m = 0; m < 4; ++m) {
            const floatx4 v4 = acc[m][n];
            ushort4v r;
#pragma unroll
            for (int j = 0; j < 4; ++j) {
                r[j] = f2bf(v4[j]);
                s += v4[j];
                q = fmaf(v4[j], v4[j], q);
            }
            *reinterpret_cast<ushort4v*>(cbase + m * 16) = r;
        }
        s += __shfl_xor(s, 16); s += __shfl_xor(s, 32);
        q += __shfl_xor(q, 16); q += __shfl_xor(q, 32);
        if ((lane >> 4) == 0) {
            atomicAdd(&sred[o], s);
            atomicAdd(&qred[o], q);
        }
    }
    __syncthreads();
    if (t < COUT) {
        atomicAdd(&gstats[t], sred[t]);
        atomicAdd(&gstats[COUT + t], qred[t]);
    }
}

// ---------------------------------------------------------------------------
// stats[0:128]=sum [128:256]=sumsq -> [256:384]=scale [384:512]=shift
// ---------------------------------------------------------------------------
__global__ __launch_bounds__(128)
void bn_finalize(float* __restrict__ stats, const float* __restrict__ gamma,
                 const float* __restrict__ beta)
{
    const int o = threadIdx.x;
    const float invN = 1.0f / (float)NROWS;
    const float mean = stats[o] * invN;
    const float var  = stats[COUT + o] * invN - mean * mean;
    const float rsig = rsqrtf(var + 1e-5f);
    const float sc   = rsig * gamma[o];
    stats[2 * COUT + o] = sc;
    stats[3 * COUT + o] = beta[o] - mean * sc;
}

// ---------------------------------------------------------------------------
// out[b,o,v] = convT[b,o,v]*scale[o] + shift[o]   (elementwise, v-contig)
// ---------------------------------------------------------------------------
__global__ __launch_bounds__(256)
void normalize_bn(const bfu* __restrict__ convT, const float* __restrict__ stats,
                  float* __restrict__ outp)
{
    const size_t i = ((size_t)blockIdx.x * 256 + threadIdx.x) * 8;
    const int ch = (int)((i / NV) & (COUT - 1));
    const float sc = stats[2 * COUT + ch];
    const float sh = stats[3 * COUT + ch];
    const short8 s = *reinterpret_cast<const short8*>(convT + i);
    float4 r0, r1;
    r0.x = fmaf(bf2f((unsigned short)s[0]), sc, sh);
    r0.y = fmaf(bf2f((unsigned short)s[1]), sc, sh);
    r0.z = fmaf(bf2f((unsigned short)s[2]), sc, sh);
    r0.w = fmaf(bf2f((unsigned short)s[3]), sc, sh);
    r1.x = fmaf(bf2f((unsigned short)s[4]), sc, sh);
    r1.y = fmaf(bf2f((unsigned short)s[5]), sc, sh);
    r1.z = fmaf(bf2f((unsigned short)s[6]), sc, sh);
    r1.w = fmaf(bf2f((unsigned short)s[7]), sc, sh);
    *reinterpret_cast<float4*>(outp + i)     = r0;
    *reinterpret_cast<float4*>(outp + i + 4) = r1;
}

// ---------------------------------------------------------------------------
extern "C" void kernel_launch(void* const* d_in, const int* in_sizes, int n_in,
                              void* d_out, int out_size, void* d_ws, size_t ws_size,
                              hipStream_t stream)
{
    (void)in_sizes; (void)n_in; (void)out_size; (void)ws_size;

    const float* x     = (const float*)d_in[0];
    const int*   cols  = (const int*)  d_in[2];
    const float* vals  = (const float*)d_in[3];
    const float* W     = (const float*)d_in[4];
    const float* gamma = (const float*)d_in[5];
    const float* beta  = (const float*)d_in[6];
    float*       out   = (float*)d_out;

    const size_t bufE = (size_t)NB * NV * CIN;      // 12,582,912 elems

    bfu* xb    = (bfu*)d_ws;
    bfu* t1    = xb + bufE;
    bfu* t2    = t1 + bufE;
    bfu* t3    = t2 + bufE;
    bfu* convT = t3 + bufE;
    bfu* Wt    = convT + bufE;                      // 65536 bf16
    float* stats = (float*)(Wt + 65536);            // 512 floats

    const dim3 blk(256);

    convert_x <<<NROWS * CIN / (256 * 8), blk, 0, stream>>>(x, xb);
    build_wt  <<<KTOT * COUT / 256, blk, 0, stream>>>(W, Wt);
    hipMemsetAsync(stats, 0, 2 * COUT * sizeof(float), stream);

    spmm_bf16 <<<NV / 2, blk, 0, stream>>>(xb, nullptr, t1, cols, vals);
    spmm_bf16 <<<NV / 2, blk, 0, stream>>>(t1, xb,      t2, cols, vals);
    spmm_bf16 <<<NV / 2, blk, 0, stream>>>(t2, t1,      t3, cols, vals);

    gemm_mfma <<<NROWS / 128, blk, 0, stream>>>(xb, t1, t2, t3, Wt, convT, stats);

    bn_finalize <<<1, 128, 0, stream>>>(stats, gamma, beta);
    normalize_bn <<<NROWS * CIN / (256 * 8), blk, 0, stream>>>(convT, stats, out);
}

// Round 3
// 172.069 us; speedup vs baseline: 2.6263x; 1.0355x over previous
//
#include <hip/hip_runtime.h>

#define NV    12288
#define CIN   128
#define COUT  128
#define DEG   9
#define NB    8
#define NROWS (NB * NV)        // 98304
#define KTOT  512              // 4 segments * 128

typedef unsigned short bfu;
typedef __attribute__((ext_vector_type(8))) short short8;
typedef __attribute__((ext_vector_type(4))) float floatx4;
typedef __attribute__((ext_vector_type(4))) unsigned short ushort4v;

__device__ __forceinline__ float bf2f(unsigned short u) {
    union { unsigned int i; float f; } x;
    x.i = ((unsigned int)u) << 16;
    return x.f;
}
__device__ __forceinline__ unsigned short f2bf(float f) {
    union { float f; unsigned int i; } x;
    x.f = f;
    unsigned int r = x.i + 0x7FFFu + ((x.i >> 16) & 1u);   // round-nearest-even
    return (unsigned short)(r >> 16);
}
__device__ __forceinline__ void gload16(const void* g, void* l) {
    __builtin_amdgcn_global_load_lds(
        (const __attribute__((address_space(1))) unsigned int*)g,
        (__attribute__((address_space(3))) unsigned int*)l, 16, 0, 0);
}

// ---------------------------------------------------------------------------
// Fused prep:
//   blocks [0, 6144)      : x fp32 -> xb bf16, 8 elems/thread
//   blocks [6144, 6400)   : W[(c*4+s)*128+o] fp32 -> Wt[o*512+s*128+c] bf16
//   block  6400           : zero stats[0..255]
// ---------------------------------------------------------------------------
__global__ __launch_bounds__(256)
void prep_kernel(const float* __restrict__ x, bfu* __restrict__ xb,
                 const float* __restrict__ W, bfu* __restrict__ Wt,
                 float* __restrict__ stats)
{
    const int blk = blockIdx.x;
    const int t   = threadIdx.x;
    if (blk < 6144) {
        const size_t i = ((size_t)blk * 256 + t) * 8;
        const float4 a = *reinterpret_cast<const float4*>(x + i);
        const float4 b = *reinterpret_cast<const float4*>(x + i + 4);
        short8 r;
        r[0] = (short)f2bf(a.x); r[1] = (short)f2bf(a.y);
        r[2] = (short)f2bf(a.z); r[3] = (short)f2bf(a.w);
        r[4] = (short)f2bf(b.x); r[5] = (short)f2bf(b.y);
        r[6] = (short)f2bf(b.z); r[7] = (short)f2bf(b.w);
        *reinterpret_cast<short8*>(xb + i) = r;
    } else if (blk < 6400) {
        const int i = (blk - 6144) * 256 + t;      // [0, 65536)
        const int o = i >> 9;
        const int kap = i & 511;
        const int s = kap >> 7;
        const int c = kap & 127;
        Wt[i] = f2bf(W[(size_t)(c * 4 + s) * COUT + o]);
    } else {
        stats[t] = 0.f;                            // t in [0,256): sum+sumsq
    }
}

// ---------------------------------------------------------------------------
// SpMM in bf16 storage, fp32 math.
//   out[b,v,c] = sum_e vals[v,e]*src[b,cols[v,e],c]          (sub==null)
//   out[b,v,c] = 2*sum - sub[b,v,c]                          (sub!=null)
// 256 thr = 2 vertices/block; thread handles (b, c0..c0+7).
// v is wave-uniform -> readfirstlane so cols/vals become s_load.
// ---------------------------------------------------------------------------
__global__ __launch_bounds__(256)
void spmm_bf16(const bfu* __restrict__ src, const bfu* __restrict__ sub,
               bfu* __restrict__ outp, const int* __restrict__ cols,
               const float* __restrict__ vals)
{
    const int t  = threadIdx.x;
    const int v  = __builtin_amdgcn_readfirstlane(blockIdx.x * 2 + (t >> 7));
    const int tt = t & 127;
    const int b  = tt >> 4;
    const int c0 = (tt & 15) * 8;

    int   ec[DEG];
    float ev[DEG];
#pragma unroll
    for (int e = 0; e < DEG; ++e) {
        ec[e] = cols[v * DEG + e];
        ev[e] = vals[v * DEG + e];
    }

    float acc[8];
#pragma unroll
    for (int j = 0; j < 8; ++j) acc[j] = 0.f;

    const size_t bbase = (size_t)b * NV * CIN;
#pragma unroll
    for (int e = 0; e < DEG; ++e) {
        const short8 s = *reinterpret_cast<const short8*>(
            src + bbase + (size_t)ec[e] * CIN + c0);
#pragma unroll
        for (int j = 0; j < 8; ++j)
            acc[j] = fmaf(ev[e], bf2f((unsigned short)s[j]), acc[j]);
    }

    if (sub != nullptr) {
        const short8 s0 = *reinterpret_cast<const short8*>(
            sub + bbase + (size_t)v * CIN + c0);
#pragma unroll
        for (int j = 0; j < 8; ++j)
            acc[j] = 2.f * acc[j] - bf2f((unsigned short)s0[j]);
    }

    short8 r;
#pragma unroll
    for (int j = 0; j < 8; ++j) r[j] = (short)f2bf(acc[j]);
    *reinterpret_cast<short8*>(outp + bbase + (size_t)v * CIN + c0) = r;
}

// ---------------------------------------------------------------------------
// MFMA GEMM: convT[b,o,v] = sum_k A[r=b*V+v, k] * Wt[o, k]   (K=512)
// A = 4 bf16 segments [98304][128]. 128x128 tile, BK=64, 4 waves (2x2),
// wave tile 64x64 = 4x4 frags of mfma_f32_16x16x32_bf16.
// LDS XOR-swizzle via pre-swizzled global_load_lds source.
// Fused BN sum/sumsq -> gstats atomics.
// ---------------------------------------------------------------------------
__global__ __launch_bounds__(256)
void gemm_mfma(const bfu* __restrict__ A0, const bfu* __restrict__ A1,
               const bfu* __restrict__ A2, const bfu* __restrict__ A3,
               const bfu* __restrict__ Wt, bfu* __restrict__ convT,
               float* __restrict__ gstats)
{
    __shared__ char smem[33792];                  // A 16K | B 16K | sred/qred 1K
    float* sred = (float*)(smem + 32768);
    float* qred = sred + COUT;

    const int t    = threadIdx.x;
    const int lane = t & 63;
    const int wid  = t >> 6;
    const int wr   = wid >> 1;                    // 0..1 row-wave
    const int wc   = wid & 1;                     // 0..1 col-wave
    const int rbase = blockIdx.x * 128;
    const int ck   = t & 7;                       // 16B chunk id for staging

    if (t < COUT) { sred[t] = 0.f; qred[t] = 0.f; }

    floatx4 acc[4][4];
#pragma unroll
    for (int m = 0; m < 4; ++m)
#pragma unroll
        for (int n = 0; n < 4; ++n) acc[m][n] = (floatx4){0.f, 0.f, 0.f, 0.f};

    const bfu* segs[4] = {A0, A1, A2, A3};

#pragma unroll
    for (int kt = 0; kt < 8; ++kt) {
        const bfu* As = segs[kt >> 1];            // unrolled -> compile-time
        const int  cb = (kt & 1) * 64;
        // stage A tile [128 rows][64 cols] bf16, source pre-swizzled
#pragma unroll
        for (int p = 0; p < 4; ++p) {
            const int flat = p * 256 + t;
            const int rr   = flat >> 3;
            gload16(As + (size_t)(rbase + rr) * CIN + cb + ((ck ^ (rr & 7)) << 3),
                    smem + flat * 16);
        }
        // stage B tile [128 o-rows][64 k] bf16 from Wt
#pragma unroll
        for (int p = 0; p < 4; ++p) {
            const int flat = p * 256 + t;
            const int n    = flat >> 3;
            gload16(Wt + (size_t)n * KTOT + kt * 64 + ((ck ^ (n & 7)) << 3),
                    smem + 16384 + flat * 16);
        }
        __syncthreads();
#pragma unroll
        for (int ks = 0; ks < 2; ++ks) {
            const int chunk = ((ks * 4 + (lane >> 4)) ^ (lane & 7)) * 16;
            short8 a[4], b[4];
#pragma unroll
            for (int m = 0; m < 4; ++m)
                a[m] = *reinterpret_cast<const short8*>(
                    smem + (wr * 64 + m * 16 + (lane & 15)) * 128 + chunk);
#pragma unroll
            for (int n = 0; n < 4; ++n)
                b[n] = *reinterpret_cast<const short8*>(
                    smem + 16384 + (wc * 64 + n * 16 + (lane & 15)) * 128 + chunk);
#pragma unroll
            for (int m = 0; m < 4; ++m)
#pragma unroll
                for (int n = 0; n < 4; ++n)
                    acc[m][n] = __builtin_amdgcn_mfma_f32_16x16x32_bf16(
                        a[m], b[n], acc[m][n], 0, 0, 0);
        }
        __syncthreads();
    }

    // epilogue: convT[b,o,v] bf16 + BN partial stats
    const int batch = rbase / NV;                 // block never straddles batch
    const int v0 = (rbase % NV) + wr * 64 + (lane >> 4) * 4;
    const int ob = wc * 64 + (lane & 15);

#pragma unroll
    for (int n = 0; n < 4; ++n) {
        const int o = ob + n * 16;
        float s = 0.f, q = 0.f;
        bfu* cbase = convT + ((size_t)batch * COUT + o) * NV + v0;
#pragma unroll
        for (int m = 0; m < 4; ++m) {
            const floatx4 v4 = acc[m][n];
            ushort4v r;
#pragma unroll
            for (int j = 0; j < 4; ++j) {
                r[j] = f2bf(v4[j]);
                s += v4[j];
                q = fmaf(v4[j], v4[j], q);
            }
            *reinterpret_cast<ushort4v*>(cbase + m * 16) = r;
        }
        s += __shfl_xor(s, 16); s += __shfl_xor(s, 32);
        q += __shfl_xor(q, 16); q += __shfl_xor(q, 32);
        if ((lane >> 4) == 0) {
            atomicAdd(&sred[o], s);
            atomicAdd(&qred[o], q);
        }
    }
    __syncthreads();
    if (t < COUT) {
        atomicAdd(&gstats[t], sred[t]);
        atomicAdd(&gstats[COUT + t], qred[t]);
    }
}

// ---------------------------------------------------------------------------
// out[b,o,v] = (convT[b,o,v]-mean[o])*rsig[o]*gamma[o] + beta[o]
// Scale/shift computed inline from raw sums (one rsqrt per thread).
// ---------------------------------------------------------------------------
__global__ __launch_bounds__(256)
void normalize_bn(const bfu* __restrict__ convT, const float* __restrict__ stats,
                  const float* __restrict__ gamma, const float* __restrict__ beta,
                  float* __restrict__ outp)
{
    const size_t i = ((size_t)blockIdx.x * 256 + threadIdx.x) * 8;
    const int ch = (int)((i / NV) & (COUT - 1));   // 8 | NV -> uniform per thread
    const float invN = 1.0f / (float)NROWS;
    const float mean = stats[ch] * invN;
    const float var  = stats[COUT + ch] * invN - mean * mean;
    const float rsig = rsqrtf(var + 1e-5f);
    const float sc   = rsig * gamma[ch];
    const float sh   = beta[ch] - mean * sc;

    const short8 s = *reinterpret_cast<const short8*>(convT + i);
    float4 r0, r1;
    r0.x = fmaf(bf2f((unsigned short)s[0]), sc, sh);
    r0.y = fmaf(bf2f((unsigned short)s[1]), sc, sh);
    r0.z = fmaf(bf2f((unsigned short)s[2]), sc, sh);
    r0.w = fmaf(bf2f((unsigned short)s[3]), sc, sh);
    r1.x = fmaf(bf2f((unsigned short)s[4]), sc, sh);
    r1.y = fmaf(bf2f((unsigned short)s[5]), sc, sh);
    r1.z = fmaf(bf2f((unsigned short)s[6]), sc, sh);
    r1.w = fmaf(bf2f((unsigned short)s[7]), sc, sh);
    *reinterpret_cast<float4*>(outp + i)     = r0;
    *reinterpret_cast<float4*>(outp + i + 4) = r1;
}

// ---------------------------------------------------------------------------
extern "C" void kernel_launch(void* const* d_in, const int* in_sizes, int n_in,
                              void* d_out, int out_size, void* d_ws, size_t ws_size,
                              hipStream_t stream)
{
    (void)in_sizes; (void)n_in; (void)out_size; (void)ws_size;

    const float* x     = (const float*)d_in[0];
    const int*   cols  = (const int*)  d_in[2];
    const float* vals  = (const float*)d_in[3];
    const float* W     = (const float*)d_in[4];
    const float* gamma = (const float*)d_in[5];
    const float* beta  = (const float*)d_in[6];
    float*       out   = (float*)d_out;

    const size_t bufE = (size_t)NB * NV * CIN;      // 12,582,912 elems

    bfu* xb    = (bfu*)d_ws;
    bfu* t1    = xb + bufE;
    bfu* t2    = t1 + bufE;
    bfu* t3    = t2 + bufE;
    bfu* convT = t3 + bufE;
    bfu* Wt    = convT + bufE;                      // 65536 bf16
    float* stats = (float*)(Wt + 65536);            // 256 floats (sum|sumsq)

    const dim3 blk(256);

    prep_kernel <<<6401, blk, 0, stream>>>(x, xb, W, Wt, stats);

    spmm_bf16 <<<NV / 2, blk, 0, stream>>>(xb, nullptr, t1, cols, vals);
    spmm_bf16 <<<NV / 2, blk, 0, stream>>>(t1, xb,      t2, cols, vals);
    spmm_bf16 <<<NV / 2, blk, 0, stream>>>(t2, t1,      t3, cols, vals);

    gemm_mfma <<<NROWS / 128, blk, 0, stream>>>(xb, t1, t2, t3, Wt, convT, stats);

    normalize_bn <<<NROWS * CIN / (256 * 8), blk, 0, stream>>>(
        convT, stats, gamma, beta, out);
}